// Round 1
// 842.503 us; speedup vs baseline: 1.0081x; 1.0081x over previous
//
#include <hip/hip_runtime.h>

typedef __bf16 bf16x8 __attribute__((ext_vector_type(8)));
typedef float f32x4 __attribute__((ext_vector_type(4)));

#define NBLOCKS 2048
#define MBLK 32

__device__ __forceinline__ unsigned short f2bf(float f) {
    unsigned u = __float_as_uint(f);
    u += 0x7fffu + ((u >> 16) & 1u);
    return (unsigned short)(u >> 16);
}

// GT[d*192+c] = bf16(gs*relu(gamma[c][d]) + gb);  biasv[d] = bs*(relu(beta[d])+1e-6) + bb
__global__ void gdn_prep(const float* __restrict__ beta_raw,
                         const float* __restrict__ gamma_raw,
                         const float* __restrict__ beta_scale,
                         const float* __restrict__ beta_bias,
                         const float* __restrict__ gamma_scale,
                         const float* __restrict__ gamma_bias,
                         const int* __restrict__ idxp,
                         unsigned short* __restrict__ GT,
                         float* __restrict__ biasv)
{
    const int idx = idxp[0];
    const float gs = fmaxf(gamma_scale[idx], 0.f);
    const float gb = fmaxf(gamma_bias[idx], 0.f);
    int t = blockIdx.x * blockDim.x + threadIdx.x;  // 0..36863
    if (t < 192 * 192) {
        int c = t / 192;
        int d = t - c * 192;
        float g = fmaxf(gamma_raw[t], 0.f);
        GT[d * 192 + c] = f2bf(gs * g + gb);
    }
    if (t < 192) {
        const float bs = fmaxf(beta_scale[idx], 0.f);
        const float bb = fmaxf(beta_bias[idx], 0.f);
        float b = fmaxf(beta_raw[t], 0.f) + 1e-6f;
        biasv[t] = bs * b + bb;
    }
}

// Swapped-operand MFMA: D = G(A) * x^2(B)  =>  D[m=d][n=pixel].
// C/D layout: col(l15) = pixel-in-tile, row(lq*4+r) = d-in-tile.
// So each lane ends up holding norm for (p = p0+16m+l15, d = d0w+16j+4lq+r):
// the epilogue is pure per-lane (reload x at those coords from L1, rsqrt, store).
// NO LDS, NO __syncthreads -> no barrier vmcnt(0) drain; waves run free and the
// compiler can overlap tile t+1 loads with tile t epilogue.
__global__ __launch_bounds__(256) void gdn_main(
    const float* __restrict__ x,
    const unsigned short* __restrict__ GT,
    const float* __restrict__ biasv,
    float* __restrict__ out,
    int ntiles)
{
    const int tid = threadIdx.x;
    const int l   = tid & 63;
    const int w   = tid >> 6;
    const int l15 = l & 15;
    const int lq  = l >> 4;
    const int d0w = w * 48;   // wave owns d in [48w, 48w+48)

    // G frag used as MFMA *A* operand: A[m=d][k=c]; lane: m=l15 -> d=d0w+16j+l15,
    // k = lq*8+e (+32kt). Same GT layout/addressing as before.
    bf16x8 Gf[3][6];
    {
        const unsigned short* g0 = GT + (d0w + l15) * 192 + lq * 8;
        #pragma unroll
        for (int j = 0; j < 3; ++j)
            #pragma unroll
            for (int kt = 0; kt < 6; ++kt)
                Gf[j][kt] = *(const bf16x8*)(g0 + j * (16 * 192) + kt * 32);
    }
    // bias for the d's this lane will hold: d = d0w + 16j + 4lq + r
    f32x4 bias4[3];
    #pragma unroll
    for (int j = 0; j < 3; ++j)
        bias4[j] = *(const f32x4*)(biasv + d0w + j * 16 + lq * 4);

    for (int tile = blockIdx.x; tile < ntiles; tile += NBLOCKS) {
        const int p0 = tile * MBLK;
        const int rowbase = (p0 + l15) * 192;   // < 2^27, int-safe

        f32x4 acc[2][3];
        #pragma unroll
        for (int m = 0; m < 2; ++m)
            #pragma unroll
            for (int j = 0; j < 3; ++j)
                acc[m][j] = (f32x4){0.f, 0.f, 0.f, 0.f};

        // x^2 frag used as MFMA *B* operand: B[k=c][n=pixel]; lane: n=l15, k=lq*8+e.
        // Identical per-lane load pattern to the old A-frag.
        #pragma unroll
        for (int kt = 0; kt < 6; ++kt) {
            #pragma unroll
            for (int m = 0; m < 2; ++m) {
                const float* xp = x + rowbase + m * (16 * 192) + kt * 32 + lq * 8;
                f32x4 a0 = *(const f32x4*)xp;
                f32x4 a1 = *(const f32x4*)(xp + 4);
                bf16x8 s;
                #pragma unroll
                for (int e = 0; e < 4; ++e) {
                    s[e]     = (__bf16)(a0[e] * a0[e]);
                    s[e + 4] = (__bf16)(a1[e] * a1[e]);
                }
                #pragma unroll
                for (int j = 0; j < 3; ++j)
                    acc[m][j] = __builtin_amdgcn_mfma_f32_16x16x32_bf16(
                        Gf[j][kt], s, acc[m][j], 0, 0, 0);
            }
        }

        // Epilogue: per-lane. x reload hits L1 (this block just streamed these
        // lines); 4 lanes (lq=0..3) cover one 64B sector -> fully coalesced.
        #pragma unroll
        for (int m = 0; m < 2; ++m) {
            #pragma unroll
            for (int j = 0; j < 3; ++j) {
                const int off = rowbase + m * (16 * 192) + d0w + j * 16 + lq * 4;
                f32x4 xv = *(const f32x4*)(x + off);
                f32x4 ov;
                #pragma unroll
                for (int r = 0; r < 4; ++r)
                    ov[r] = xv[r] * __builtin_amdgcn_rsqf(acc[m][j][r] + bias4[j][r]);
                *(f32x4*)(out + off) = ov;
            }
        }
    }
}

extern "C" void kernel_launch(void* const* d_in, const int* in_sizes, int n_in,
                              void* d_out, int out_size, void* d_ws, size_t ws_size,
                              hipStream_t stream)
{
    const float* x           = (const float*)d_in[0];
    const float* beta_raw    = (const float*)d_in[1];
    const float* gamma_raw   = (const float*)d_in[2];
    const float* beta_scale  = (const float*)d_in[3];
    const float* beta_bias   = (const float*)d_in[4];
    const float* gamma_scale = (const float*)d_in[5];
    const float* gamma_bias  = (const float*)d_in[6];
    const int*   idxp        = (const int*)d_in[7];
    float*       out         = (float*)d_out;

    unsigned short* GT    = (unsigned short*)d_ws;
    float*          biasv = (float*)((char*)d_ws + 192 * 192 * sizeof(unsigned short));

    gdn_prep<<<144, 256, 0, stream>>>(beta_raw, gamma_raw, beta_scale, beta_bias,
                                      gamma_scale, gamma_bias, idxp, GT, biasv);

    const int P = out_size / 192;       // 524288 pixels
    const int ntiles = P / MBLK;        // 16384
    gdn_main<<<NBLOCKS, 256, 0, stream>>>(x, GT, biasv, out, ntiles);
}

// Round 3
// 659.572 us; speedup vs baseline: 1.2877x; 1.2773x over previous
//
#include <hip/hip_runtime.h>

typedef __bf16 bf16x8 __attribute__((ext_vector_type(8)));
typedef float f32x4 __attribute__((ext_vector_type(4)));

#define NBLOCKS 2048
#define MBLK 32
#define RSTRIDE 196   // f32 elems; rinv transpose buffer row stride

__device__ __forceinline__ unsigned short f2bf(float f) {
    unsigned u = __float_as_uint(f);
    u += 0x7fffu + ((u >> 16) & 1u);
    return (unsigned short)(u >> 16);
}

// GT[d*192+c] = bf16(gs*relu(gamma[c][d]) + gb);  biasv[d] = bs*(relu(beta[d])+1e-6) + bb
__global__ void gdn_prep(const float* __restrict__ beta_raw,
                         const float* __restrict__ gamma_raw,
                         const float* __restrict__ beta_scale,
                         const float* __restrict__ beta_bias,
                         const float* __restrict__ gamma_scale,
                         const float* __restrict__ gamma_bias,
                         const int* __restrict__ idxp,
                         unsigned short* __restrict__ GT,
                         float* __restrict__ biasv)
{
    const int idx = idxp[0];
    const float gs = fmaxf(gamma_scale[idx], 0.f);
    const float gb = fmaxf(gamma_bias[idx], 0.f);
    int t = blockIdx.x * blockDim.x + threadIdx.x;  // 0..36863
    if (t < 192 * 192) {
        int c = t / 192;
        int d = t - c * 192;
        float g = fmaxf(gamma_raw[t], 0.f);
        GT[d * 192 + c] = f2bf(gs * g + gb);
    }
    if (t < 192) {
        const float bs = fmaxf(beta_scale[idx], 0.f);
        const float bb = fmaxf(beta_bias[idx], 0.f);
        float b = fmaxf(beta_raw[t], 0.f) + 1e-6f;
        biasv[t] = bs * b + bb;
    }
}

// Per tile (32 px):
//   1. coalesced cooperative load of x-tile -> regs (issued a tile ahead),
//      square+cvt -> bf16 in XOR-swizzled LDS (shared by all 4 waves)
//   2. each wave ds_read_b128 its A-frags, MFMA vs its private GT B-frags
//   3. rsqrt -> rinv LDS transpose, coalesced epilogue: out = x(regs) * rinv
// Global traffic: x read ONCE (coalesced), out written once (coalesced).
__global__ __launch_bounds__(256) void gdn_main(
    const float* __restrict__ x,
    const unsigned short* __restrict__ GT,
    const float* __restrict__ biasv,
    float* __restrict__ out,
    int ntiles)
{
    __shared__ __align__(16) unsigned char xsq[MBLK * 384];  // bf16 [32][192], XOR-swizzled
    __shared__ float lrinv[MBLK * RSTRIDE];

    const int tid = threadIdx.x;
    const int l   = tid & 63;
    const int w   = tid >> 6;
    const int l15 = l & 15;
    const int lq  = l >> 4;
    const int d0w = w * 48;            // wave owns d in [48w, 48w+48)
    const int rsw = (l15 & 7) << 4;    // frag-read XOR mask (row&7 == l15&7)

    // B frag: B[k=c][n=d], lane: n=l15, k=lq*8+e  -> GT row (d), 16B contiguous
    bf16x8 Bf[3][6];
    {
        const unsigned short* g0 = GT + (d0w + l15) * 192 + lq * 8;
        #pragma unroll
        for (int j = 0; j < 3; ++j)
            #pragma unroll
            for (int kt = 0; kt < 6; ++kt)
                Bf[j][kt] = *(const bf16x8*)(g0 + j * (16 * 192) + kt * 32);
    }
    float biasl[3];
    #pragma unroll
    for (int j = 0; j < 3; ++j) biasl[j] = biasv[d0w + j * 16 + l15];

    // stage/epilogue mapping: thread covers 8 consecutive floats per i
    // q = tid + 256*i, row = q/24, chunk c = q%24 (8 floats)
    int srow[3], scol[3], swzb[3];
    #pragma unroll
    for (int i = 0; i < 3; ++i) {
        int q = tid + 256 * i;
        int r = q / 24;
        int c = q - r * 24;
        srow[i] = r;
        scol[i] = c * 8;                                  // float col
        swzb[i] = r * 384 + ((c * 16) ^ ((r & 7) << 4));  // swizzled LDS byte addr
    }

    f32x4 xv[6];   // current tile's x values (8 floats per i), live until epilogue

    // ---- prologue: stage tile[blockIdx.x] ----
    {
        const float* xp = x + blockIdx.x * (MBLK * 192);
        #pragma unroll
        for (int i = 0; i < 3; ++i) {
            xv[2 * i]     = *(const f32x4*)(xp + tid * 8 + i * 2048);
            xv[2 * i + 1] = *(const f32x4*)(xp + tid * 8 + i * 2048 + 4);
        }
        #pragma unroll
        for (int i = 0; i < 3; ++i) {
            bf16x8 s;
            #pragma unroll
            for (int e = 0; e < 4; ++e) {
                s[e]     = (__bf16)(xv[2 * i][e] * xv[2 * i][e]);
                s[e + 4] = (__bf16)(xv[2 * i + 1][e] * xv[2 * i + 1][e]);
            }
            *(bf16x8*)(xsq + swzb[i]) = s;
        }
    }
    __syncthreads();

    for (int tile = blockIdx.x; tile < ntiles; tile += NBLOCKS) {
        const int p0 = tile * MBLK;
        const bool has_next = (tile + NBLOCKS) < ntiles;

        // issue next tile's global loads NOW: latency hides under MFMA phase
        f32x4 nxv[6];
        if (has_next) {
            const float* xp = x + (tile + NBLOCKS) * (MBLK * 192);
            #pragma unroll
            for (int i = 0; i < 3; ++i) {
                nxv[2 * i]     = *(const f32x4*)(xp + tid * 8 + i * 2048);
                nxv[2 * i + 1] = *(const f32x4*)(xp + tid * 8 + i * 2048 + 4);
            }
        }

        f32x4 acc[2][3];
        #pragma unroll
        for (int m = 0; m < 2; ++m)
            #pragma unroll
            for (int j = 0; j < 3; ++j)
                acc[m][j] = (f32x4){0.f, 0.f, 0.f, 0.f};

        // A frags from swizzled LDS: A[m=pixel l15(+16m)][k=lq*8+e (+32kt)]
        #pragma unroll
        for (int kt = 0; kt < 6; ++kt) {
            const int cb = (kt * 64 + lq * 16) ^ rsw;
            bf16x8 s0 = *(const bf16x8*)(xsq + l15 * 384 + cb);
            bf16x8 s1 = *(const bf16x8*)(xsq + l15 * 384 + 6144 + cb);
            #pragma unroll
            for (int j = 0; j < 3; ++j) {
                acc[0][j] = __builtin_amdgcn_mfma_f32_16x16x32_bf16(s0, Bf[j][kt], acc[0][j], 0, 0, 0);
                acc[1][j] = __builtin_amdgcn_mfma_f32_16x16x32_bf16(s1, Bf[j][kt], acc[1][j], 0, 0, 0);
            }
        }

        __syncthreads();  // frag reads done -> xsq overwritable; prev epilogue rinv reads done

        // rinv transpose: C/D col(d)=l15, row(pixel)=lq*4+r
        #pragma unroll
        for (int m = 0; m < 2; ++m)
            #pragma unroll
            for (int j = 0; j < 3; ++j) {
                float* lp = &lrinv[(m * 16 + lq * 4) * RSTRIDE + d0w + j * 16 + l15];
                #pragma unroll
                for (int r = 0; r < 4; ++r)
                    lp[r * RSTRIDE] = __builtin_amdgcn_rsqf(acc[m][j][r] + biasl[j]);
            }

        // stage next tile into xsq (region free since the frag-read barrier)
        if (has_next) {
            #pragma unroll
            for (int i = 0; i < 3; ++i) {
                bf16x8 s;
                #pragma unroll
                for (int e = 0; e < 4; ++e) {
                    s[e]     = (__bf16)(nxv[2 * i][e] * nxv[2 * i][e]);
                    s[e + 4] = (__bf16)(nxv[2 * i + 1][e] * nxv[2 * i + 1][e]);
                }
                *(bf16x8*)(xsq + swzb[i]) = s;
            }
        }

        __syncthreads();  // rinv + next xsq visible

        // epilogue: out = x(regs) * rinv, fully coalesced stores
        {
            float* op = out + p0 * 192;
            #pragma unroll
            for (int i = 0; i < 3; ++i) {
                f32x4 r0 = *(const f32x4*)&lrinv[srow[i] * RSTRIDE + scol[i]];
                f32x4 r1 = *(const f32x4*)&lrinv[srow[i] * RSTRIDE + scol[i] + 4];
                f32x4 o0, o1;
                #pragma unroll
                for (int h = 0; h < 4; ++h) {
                    o0[h] = xv[2 * i][h] * r0[h];
                    o1[h] = xv[2 * i + 1][h] * r1[h];
                }
                *(f32x4*)(op + tid * 8 + i * 2048)     = o0;
                *(f32x4*)(op + tid * 8 + i * 2048 + 4) = o1;
            }
        }

        if (has_next) {
            #pragma unroll
            for (int e = 0; e < 6; ++e) xv[e] = nxv[e];
        }
    }
}

extern "C" void kernel_launch(void* const* d_in, const int* in_sizes, int n_in,
                              void* d_out, int out_size, void* d_ws, size_t ws_size,
                              hipStream_t stream)
{
    const float* x           = (const float*)d_in[0];
    const float* beta_raw    = (const float*)d_in[1];
    const float* gamma_raw   = (const float*)d_in[2];
    const float* beta_scale  = (const float*)d_in[3];
    const float* beta_bias   = (const float*)d_in[4];
    const float* gamma_scale = (const float*)d_in[5];
    const float* gamma_bias  = (const float*)d_in[6];
    const int*   idxp        = (const int*)d_in[7];
    float*       out         = (float*)d_out;

    unsigned short* GT    = (unsigned short*)d_ws;
    float*          biasv = (float*)((char*)d_ws + 192 * 192 * sizeof(unsigned short));

    gdn_prep<<<144, 256, 0, stream>>>(beta_raw, gamma_raw, beta_scale, beta_bias,
                                      gamma_scale, gamma_bias, idxp, GT, biasv);

    const int P = out_size / 192;       // 524288 pixels
    const int ntiles = P / MBLK;        // 16384
    gdn_main<<<NBLOCKS, 256, 0, stream>>>(x, GT, biasv, out, ntiles);
}